// Round 15
// baseline (39.109 us; speedup 1.0000x reference)
//
#include <hip/hip_runtime.h>

#define BB 32
#define SS 512
#define FF 256
#define NN 8
#define LC 32               // chunk length
#define NJ 16               // chunks = SS/LC
#define VST1 132            // k1 vs row stride (16*8 payload + 4)

// ---------------- kernel 1: 16 chunk-boundary states per channel -> ws ----------------
// ws[b][j][f][n] = state entering chunk j of channel (b,f); ws[b][0][*] = 0.
__global__ __launch_bounds__(256) void hippo_states16(
    const float* __restrict__ x,
    const float* __restrict__ Ad,
    const float* __restrict__ Bd,
    float* __restrict__ ws)
{
    __shared__ __align__(16) float vs[NJ * VST1];     // 8.4 KB
    __shared__ __align__(16) float pw2[4][64];        // M^(32*2^k), k=0..3
    __shared__ __align__(16) float Mp[5][64];         // M^1,2,4,8,16
    __shared__ __align__(16) float Ks[LC][NN];        // K[i] = M^(31-i) B

    const int tid = threadIdx.x;
    const int h   = blockIdx.x;                 // 512 blocks
    const int g   = (h & 7) * 64 + (h >> 3);    // XCD-chunked swizzle
    const int b   = g >> 4;
    const int f0  = (g & 15) * 16;

    if (tid < 64) {
        const int m = tid >> 3, n = tid & 7;
        Mp[0][tid] = Ad[n * NN + m];                     // M = A^T
#pragma unroll
        for (int s = 1; s < 5; ++s) {                    // M^2..M^16
            float a = 0.f;
#pragma unroll
            for (int t = 0; t < 8; ++t) a = fmaf(Mp[s-1][m*8+t], Mp[s-1][t*8+n], a);
            Mp[s][tid] = a;
        }
        {   float a = 0.f;                               // M^32
#pragma unroll
            for (int t = 0; t < 8; ++t) a = fmaf(Mp[4][m*8+t], Mp[4][t*8+n], a);
            pw2[0][tid] = a; }
#pragma unroll
        for (int k = 1; k < 4; ++k) {                    // M^64..M^256
            float a = 0.f;
#pragma unroll
            for (int t = 0; t < 8; ++t) a = fmaf(pw2[k-1][m*8+t], pw2[k-1][t*8+n], a);
            pw2[k][tid] = a;
        }
        if (tid < LC) {                                  // K[i] = M^(31-i) B
            const int e = LC - 1 - tid;                  // 5 bits
            float v[8];
#pragma unroll
            for (int q = 0; q < 8; ++q) v[q] = Bd[q];
#pragma unroll
            for (int s = 0; s < 5; ++s) {
                if (e & (1 << s)) {
                    float nv[8];
#pragma unroll
                    for (int r = 0; r < 8; ++r) {
                        float a = 0.f;
#pragma unroll
                        for (int c2 = 0; c2 < 8; ++c2)
                            a = fmaf(Mp[s][r * 8 + c2], v[c2], a);
                        nv[r] = a;
                    }
#pragma unroll
                    for (int r = 0; r < 8; ++r) v[r] = nv[r];
                }
            }
#pragma unroll
            for (int r = 0; r < 8; ++r) Ks[tid][r] = v[r];
        }
    }
    __syncthreads();

    // ---- phase 1: chunk-end state from zero (Krylov over 32 steps) ----
    const int j  = tid >> 4;            // chunk 0..15
    const int ch = tid & 15;            // channel-in-block
    {
        const float* xp = x + ((size_t)b * SS + j * LC) * FF + f0 + ch;
        float c[NN];
#pragma unroll
        for (int m = 0; m < NN; ++m) c[m] = 0.f;
#pragma unroll
        for (int i = 0; i < LC; ++i) {
            const float xt = xp[(size_t)i * FF];
            const float4 k0 = *(const float4*)&Ks[i][0];
            const float4 k1 = *(const float4*)&Ks[i][4];
            c[0] = fmaf(k0.x, xt, c[0]); c[1] = fmaf(k0.y, xt, c[1]);
            c[2] = fmaf(k0.z, xt, c[2]); c[3] = fmaf(k0.w, xt, c[3]);
            c[4] = fmaf(k1.x, xt, c[4]); c[5] = fmaf(k1.y, xt, c[5]);
            c[6] = fmaf(k1.z, xt, c[6]); c[7] = fmaf(k1.w, xt, c[7]);
        }
        float* vj = &vs[j * VST1 + ch * NN];
        *(float4*)(vj)     = make_float4(c[0], c[1], c[2], c[3]);
        *(float4*)(vj + 4) = make_float4(c[4], c[5], c[6], c[7]);
    }
    __syncthreads();

    // ---- phase 2: in-wave scan over 16 chunks (4 shfl levels) ----
    {
        const int w  = tid >> 6;          // wave 0..3 -> 4 channels each
        const int l  = tid & 63;
        const int js = l >> 2;            // chunk 0..15
        const int cs = w * 4 + (l & 3);   // channel 0..15

        float s[NN];
        {
            const float* vp = &vs[js * VST1 + cs * NN];
            float4 p0 = *(const float4*)(vp);
            float4 p1 = *(const float4*)(vp + 4);
            s[0] = p0.x; s[1] = p0.y; s[2] = p0.z; s[3] = p0.w;
            s[4] = p1.x; s[5] = p1.y; s[6] = p1.z; s[7] = p1.w;
        }
#pragma unroll
        for (int k = 0; k < 4; ++k) {
            const int d = 1 << k;
            float prev[NN];
#pragma unroll
            for (int m = 0; m < NN; ++m) prev[m] = __shfl_up(s[m], 4 * d, 64);
            if (js >= d) {
#pragma unroll
                for (int m = 0; m < NN; ++m) {
                    const float4 r0 = *(const float4*)&pw2[k][m * 8];
                    const float4 r1 = *(const float4*)&pw2[k][m * 8 + 4];
                    float a = s[m];
                    a = fmaf(r0.x, prev[0], a); a = fmaf(r0.y, prev[1], a);
                    a = fmaf(r0.z, prev[2], a); a = fmaf(r0.w, prev[3], a);
                    a = fmaf(r1.x, prev[4], a); a = fmaf(r1.y, prev[5], a);
                    a = fmaf(r1.z, prev[6], a); a = fmaf(r1.w, prev[7], a);
                    s[m] = a;
                }
            }
        }
        // inclusive of js = incoming of js+1; js==15 seeds chunk 0 with zeros
        if (js < NJ - 1) {
            float4* w4 = (float4*)(ws + (((size_t)b * NJ + js + 1) * FF + f0 + cs) * NN);
            w4[0] = make_float4(s[0], s[1], s[2], s[3]);
            w4[1] = make_float4(s[4], s[5], s[6], s[7]);
        } else {
            float4* w4 = (float4*)(ws + (((size_t)b * NJ + 0) * FF + f0 + cs) * NN);
            w4[0] = make_float4(0.f, 0.f, 0.f, 0.f);
            w4[1] = make_float4(0.f, 0.f, 0.f, 0.f);
        }
    }
}

// ---------------- kernel 2: address-ordered emit, dense 1KB wave stores ----------------
// block = (b, chunk j): 512 threads; thread = half-channel (p=tid&1 owns states 4p..4p+3).
// Per step t the block writes the full 8KB row at out[(b,t0+t),:,:] in order; t ascends,
// so each block fills its 256KB output region near-sequentially.
__global__ __launch_bounds__(512) void hippo_emit_row(
    const float* __restrict__ x,
    const float* __restrict__ Ad,
    const float* __restrict__ Bd,
    const float* __restrict__ ws,
    float* __restrict__ out)
{
    const int tid = threadIdx.x;
    const int p   = tid & 1;
    const int ch  = tid >> 1;                   // 0..255
    const int h   = blockIdx.x;                 // 512 blocks
    const int g   = (h & 7) * 64 + (h >> 3);    // XCD-chunked swizzle
    const int b   = g >> 4;
    const int j   = g & 15;
    const int t0  = j * LC;

    // per-parity A block (8x4) and B half (L1-cached, uniform-ish)
    float4 Ar[8];
#pragma unroll
    for (int r = 0; r < 8; ++r) {
        const int n = (r + p * 4) & 7;
        Ar[r] = *(const float4*)(Ad + n * NN + p * 4);
    }
    const float4 Bv4 = *(const float4*)(Bd + p * 4);

    // incoming state: own half is a dense float4; partner half via shfl_xor(1)
    float c[8];
    {
        const float4* w4 = (const float4*)(ws + (((size_t)b * NJ + j) * FF + ch) * NN + p * 4);
        float4 own = *w4;
        c[0] = own.x; c[1] = own.y; c[2] = own.z; c[3] = own.w;
#pragma unroll
        for (int q = 0; q < 4; ++q) c[4 + q] = __shfl_xor(c[q], 1);
    }

    const float* xp = x + ((size_t)b * SS + t0) * FF + ch;
    float* ob = out + ((size_t)b * SS + t0) * (FF * NN) + tid * 4;

#pragma unroll 4
    for (int t = 0; t < LC; ++t) {
        const float xt = xp[(size_t)t * FF];
        float cn[4];
#pragma unroll
        for (int m = 0; m < 4; ++m) {
            float a = ((const float*)&Bv4)[m] * xt;
#pragma unroll
            for (int r = 0; r < 8; ++r)
                a = fmaf(((const float*)&Ar[r])[m], c[r], a);
            cn[m] = a;
        }

        *(float4*)(ob + (size_t)t * (FF * NN)) = make_float4(cn[0], cn[1], cn[2], cn[3]);

#pragma unroll
        for (int q = 0; q < 4; ++q) {
            c[4 + q] = __shfl_xor(cn[q], 1);
            c[q] = cn[q];
        }
    }
}

extern "C" void kernel_launch(void* const* d_in, const int* in_sizes, int n_in,
                              void* d_out, int out_size, void* d_ws, size_t ws_size,
                              hipStream_t stream) {
    const float* x  = (const float*)d_in[0];
    const float* Ad = (const float*)d_in[1];
    const float* Bd = (const float*)d_in[2];
    float* out = (float*)d_out;
    float* ws  = (float*)d_ws;   // BB*NJ*FF*NN*4 = 4 MiB

    const int grid1 = BB * NJ;   // 512 blocks x 256 threads
    hipLaunchKernelGGL(hippo_states16, dim3(grid1), dim3(256), 0, stream,
                       x, Ad, Bd, ws);

    const int grid2 = BB * NJ;   // 512 blocks x 512 threads
    hipLaunchKernelGGL(hippo_emit_row, dim3(grid2), dim3(512), 0, stream,
                       x, Ad, Bd, ws, out);
}

// Round 16
// 36.286 us; speedup vs baseline: 1.0778x; 1.0778x over previous
//
#include <hip/hip_runtime.h>

#define BB 32
#define SS 512
#define FF 256
#define NN 8
#define L 16               // chunk length
#define NCH 32             // SS/L
#define CGF 8              // channels per block
#define NTF 256            // threads per block
#define VST 68             // vs row stride (words): 64 payload + 4 (R13 lesson)

__global__ __launch_bounds__(NTF) void hippo_fused6(
    const float* __restrict__ x,
    const float* __restrict__ Ad,
    const float* __restrict__ Bd,
    float* __restrict__ out)
{
    __shared__ __align__(16) float vs[NCH * VST];     // 8.7 KB
    __shared__ __align__(16) float pw[5][64];         // M^(16*2^k), k=0..4
    __shared__ __align__(16) float Mp[4][64];         // M^1,2,4,8
    __shared__ __align__(16) float Ks[L][NN];         // K[i] = M^(15-i) B

    const int tid = threadIdx.x;

    // XCD-chunked swizzle
    const int h  = blockIdx.x;
    const int g  = (h & 7) * 128 + (h >> 3);
    const int b  = g >> 5;
    const int f0 = (g & 31) * CGF;

    const int j  = tid >> 3;            // chunk 0..31
    const int ch = tid & 7;             // channel-in-block
    const int t0 = j * L;

    // ---- x for this thread's chunk: 16 registers, loaded ONCE, used twice ----
    const float* xp = x + ((size_t)b * SS + t0) * FF + f0 + ch;
    float xv[L];
#pragma unroll
    for (int i = 0; i < L; ++i) xv[i] = xp[(size_t)i * FF];

    // ---- wave 0: matrix algebra (overlaps the loads above) ----
    if (tid < 64) {
        const int m = tid >> 3, n = tid & 7;
        Mp[0][tid] = Ad[n * NN + m];                 // M = A^T
#pragma unroll
        for (int s = 1; s < 4; ++s) {                // M^2, M^4, M^8
            float a = 0.f;
#pragma unroll
            for (int t = 0; t < 8; ++t) a = fmaf(Mp[s-1][m*8+t], Mp[s-1][t*8+n], a);
            Mp[s][tid] = a;
        }
        {   float a = 0.f;                           // M^16
#pragma unroll
            for (int t = 0; t < 8; ++t) a = fmaf(Mp[3][m*8+t], Mp[3][t*8+n], a);
            pw[0][tid] = a; }
#pragma unroll
        for (int k = 1; k < 5; ++k) {                // M^32..M^256
            float a = 0.f;
#pragma unroll
            for (int t = 0; t < 8; ++t) a = fmaf(pw[k-1][m*8+t], pw[k-1][t*8+n], a);
            pw[k][tid] = a;
        }
        if (tid < L) {                               // K[i] = M^(15-i) B
            const int e = L - 1 - tid;               // 4 bits
            float v[8];
#pragma unroll
            for (int q = 0; q < 8; ++q) v[q] = Bd[q];
#pragma unroll
            for (int s = 0; s < 4; ++s) {
                if (e & (1 << s)) {
                    float nv[8];
#pragma unroll
                    for (int r = 0; r < 8; ++r) {
                        float a = 0.f;
#pragma unroll
                        for (int c2 = 0; c2 < 8; ++c2)
                            a = fmaf(Mp[s][r * 8 + c2], v[c2], a);
                        nv[r] = a;
                    }
#pragma unroll
                    for (int r = 0; r < 8; ++r) v[r] = nv[r];
                }
            }
#pragma unroll
            for (int r = 0; r < 8; ++r) Ks[tid][r] = v[r];
        }
    }

    // thread-uniform A/B -> scalar regs (for emit)
    float As[NN * NN];
#pragma unroll
    for (int i = 0; i < NN * NN; ++i) As[i] = Ad[i];
    float Bv[NN];
#pragma unroll
    for (int m = 0; m < NN; ++m) Bv[m] = Bd[m];

    __syncthreads();   // barrier 1: algebra ready (x already in registers)

    // ---- phase 1: chunk-end state from zero via Krylov sum (x from regs) ----
    {
        float c[NN];
#pragma unroll
        for (int m = 0; m < NN; ++m) c[m] = 0.f;
#pragma unroll
        for (int i = 0; i < L; ++i) {
            const float xt = xv[i];
            const float4 k0 = *(const float4*)&Ks[i][0];
            const float4 k1 = *(const float4*)&Ks[i][4];
            c[0] = fmaf(k0.x, xt, c[0]); c[1] = fmaf(k0.y, xt, c[1]);
            c[2] = fmaf(k0.z, xt, c[2]); c[3] = fmaf(k0.w, xt, c[3]);
            c[4] = fmaf(k1.x, xt, c[4]); c[5] = fmaf(k1.y, xt, c[5]);
            c[6] = fmaf(k1.z, xt, c[6]); c[7] = fmaf(k1.w, xt, c[7]);
        }
        float* vj = &vs[j * VST + ch * NN];
        *(float4*)(vj)     = make_float4(c[0], c[1], c[2], c[3]);
        *(float4*)(vj + 4) = make_float4(c[4], c[5], c[6], c[7]);
    }
    __syncthreads();   // barrier 2: chunk-end states in vs

    // ---- phase 2: in-wave shfl Hillis-Steele (wave w owns ch {2w,2w+1}) ----
    {
        const int lane = tid & 63;
        const int w    = tid >> 6;
        const int js   = lane >> 1;
        const int cs   = 2 * w + (lane & 1);

        float s[NN];
        {
            const float* vp = &vs[js * VST + cs * NN];
            float4 p0 = *(const float4*)(vp);
            float4 p1 = *(const float4*)(vp + 4);
            s[0] = p0.x; s[1] = p0.y; s[2] = p0.z; s[3] = p0.w;
            s[4] = p1.x; s[5] = p1.y; s[6] = p1.z; s[7] = p1.w;
        }
#pragma unroll
        for (int k = 0; k < 5; ++k) {
            const int d = 1 << k;
            float prev[NN];
#pragma unroll
            for (int m = 0; m < NN; ++m) prev[m] = __shfl_up(s[m], 2 * d, 64);
            if (js >= d) {
#pragma unroll
                for (int m = 0; m < NN; ++m) {
                    const float4 r0 = *(const float4*)&pw[k][m * 8];
                    const float4 r1 = *(const float4*)&pw[k][m * 8 + 4];
                    float a = s[m];
                    a = fmaf(r0.x, prev[0], a); a = fmaf(r0.y, prev[1], a);
                    a = fmaf(r0.z, prev[2], a); a = fmaf(r0.w, prev[3], a);
                    a = fmaf(r1.x, prev[4], a); a = fmaf(r1.y, prev[5], a);
                    a = fmaf(r1.z, prev[6], a); a = fmaf(r1.w, prev[7], a);
                    s[m] = a;
                }
            }
        }
        float* vj = &vs[js * VST + cs * NN];
        *(float4*)(vj)     = make_float4(s[0], s[1], s[2], s[3]);
        *(float4*)(vj + 4) = make_float4(s[4], s[5], s[6], s[7]);
    }
    __syncthreads();   // barrier 3: inclusive prefixes in vs

    // ---- phase 3: emit chunk j from incoming state (x from regs, pure FMA) ----
    float ci[NN];
    if (j > 0) {
        const float* vp = &vs[(j - 1) * VST + ch * NN];
        float4 p0 = *(const float4*)(vp);
        float4 p1 = *(const float4*)(vp + 4);
        ci[0] = p0.x; ci[1] = p0.y; ci[2] = p0.z; ci[3] = p0.w;
        ci[4] = p1.x; ci[5] = p1.y; ci[6] = p1.z; ci[7] = p1.w;
    } else {
#pragma unroll
        for (int m = 0; m < NN; ++m) ci[m] = 0.f;
    }

    float* op = out + (((size_t)b * SS + t0) * FF + f0 + ch) * NN;
#pragma unroll
    for (int i = 0; i < L; ++i) {
        const float xt = xv[i];
        float cn[NN];
#pragma unroll
        for (int m = 0; m < NN; ++m) {
            float a = Bv[m] * xt;
#pragma unroll
            for (int n = 0; n < NN; ++n) a = fmaf(As[n * NN + m], ci[n], a);
            cn[m] = a;
        }
#pragma unroll
        for (int m = 0; m < NN; ++m) ci[m] = cn[m];

        float4* o4 = (float4*)(op + (size_t)i * (FF * NN));
        o4[0] = make_float4(ci[0], ci[1], ci[2], ci[3]);
        o4[1] = make_float4(ci[4], ci[5], ci[6], ci[7]);
    }
}

extern "C" void kernel_launch(void* const* d_in, const int* in_sizes, int n_in,
                              void* d_out, int out_size, void* d_ws, size_t ws_size,
                              hipStream_t stream) {
    const float* x  = (const float*)d_in[0];
    const float* Ad = (const float*)d_in[1];
    const float* Bd = (const float*)d_in[2];
    float* out = (float*)d_out;

    const int grid = BB * (FF / CGF);   // 1024 blocks x 256 threads
    hipLaunchKernelGGL(hippo_fused6, dim3(grid), dim3(NTF), 0, stream,
                       x, Ad, Bd, out);
}